// Round 16
// baseline (168.439 us; speedup 1.0000x reference)
//
#include <hip/hip_runtime.h>
#include <stdint.h>

// conv2d 3x3 s1 p1, NCHW fp32, N=16 C=K=64 H=W=224. Implicit GEMM bf16 MFMA 32x32x16.
// R16 = R15 (= R10 structure + all-36-resident weights; 161.6-161.8us plateau) plus:
//  (a) wprep merged into xprep (first 144 blocks also convert weights; one less dispatch)
//  (b) ISOLATED XCD-chunked bid swizzle on conv (R13 bundled it with setprio; retry alone)
// Fallback to R8-style VGPR-staging conv (with separate wprep) when ws too small.

#define HH 224
#define WW 224
#define CHW (HH * WW)
#define PLANE 4352           // 34 w * 64 c * 2 B
#define NSLOT 18
#define XT_ROWB 28928        // 226 wp * 64 c * 2 B per (n,hp) row
#define XT_NB   6537728      // 226 * XT_ROWB per n
#define WB_BYTES 73728
#define WS_NEED (WB_BYTES + 16 * (size_t)XT_NB)   // 104,677,376

typedef short bf16x8 __attribute__((ext_vector_type(8)));
typedef float f32x16 __attribute__((ext_vector_type(16)));
typedef __attribute__((address_space(1))) const char GCHAR;
typedef __attribute__((address_space(3))) char LCHAR;

__device__ __forceinline__ unsigned short f2bf(float f) {
    union { float f; unsigned int u; } v; v.f = f;
    unsigned int u = v.u;
    return (unsigned short)((u + 0x7fffu + ((u >> 16) & 1u)) >> 16);  // RNE
}

#define SGB  __builtin_amdgcn_sched_group_barrier
#define MFMA __builtin_amdgcn_mfma_f32_32x32x16_bf16

__device__ __forceinline__ void block_fence_lds() {
    asm volatile("s_waitcnt lgkmcnt(0)" ::: "memory");
    __builtin_amdgcn_s_barrier();
    __builtin_amdgcn_sched_barrier(0);
}

// ---------------- weight prep body (shared) ----------------
__device__ __forceinline__ void wprep_body(int i, const float* __restrict__ wgt,
                                           unsigned short* __restrict__ wb) {
    const int j   = i & 7;
    const int oc  = (i >> 3) & 63;
    const int g   = (i >> 9) & 1;
    const int ks  = i >> 10;
    const int tap = ks >> 2;
    const int c   = (ks & 3) * 16 + g * 8 + j;
    wb[i] = f2bf(wgt[(oc * 64 + c) * 9 + tap]);
}

__global__ void wprep_kernel(const float* __restrict__ wgt, unsigned short* __restrict__ wb) {
    const int i = blockIdx.x * 256 + threadIdx.x;
    if (i < 36864) wprep_body(i, wgt, wb);
}

// ---------------- input prep (+merged weight prep): NCHW fp32 -> padded CL bf16 ------
__global__ __launch_bounds__(256)
void xprep_kernel(const float* __restrict__ x, const float* __restrict__ wgt,
                  unsigned short* __restrict__ wb, unsigned short* __restrict__ xt) {
    __shared__ __align__(16) unsigned short tile[226 * 64];
    const int tid = threadIdx.x;
    const int b   = blockIdx.x;
    if (b < 144) wprep_body(b * 256 + tid, wgt, wb);   // merged weight prep

    const int n   = b / 226;
    const int hp  = b % 226;
    bf16x8* orow = (bf16x8*)((char*)xt + (size_t)(n * 226 + hp) * XT_ROWB);

    if (hp == 0 || hp == 225) {
        const bf16x8 z = {};
        for (int i = tid; i < 1808; i += 256) orow[i] = z;
        return;
    }
    if (tid < 64) { tile[tid] = 0; tile[225 * 64 + tid] = 0; }

    const float* xr = x + (size_t)n * 64 * CHW + (size_t)(hp - 1) * WW;
    for (int i = tid; i < 64 * 56; i += 256) {
        const int c  = i / 56;
        const int w4 = i % 56;
        const float4 v = *(const float4*)(xr + (size_t)c * CHW + w4 * 4);
        const int wp0 = w4 * 4 + 1;
        const int cb  = c * 2;
        *(unsigned short*)((char*)tile + (wp0    ) * 128 + (cb ^ ((((wp0    ) >> 2) & 7) << 4))) = f2bf(v.x);
        *(unsigned short*)((char*)tile + (wp0 + 1) * 128 + (cb ^ ((((wp0 + 1) >> 2) & 7) << 4))) = f2bf(v.y);
        *(unsigned short*)((char*)tile + (wp0 + 2) * 128 + (cb ^ ((((wp0 + 2) >> 2) & 7) << 4))) = f2bf(v.z);
        *(unsigned short*)((char*)tile + (wp0 + 3) * 128 + (cb ^ ((((wp0 + 3) >> 2) & 7) << 4))) = f2bf(v.w);
    }
    __syncthreads();
    for (int i = tid; i < 1808; i += 256) {
        const int wp = i >> 3, k = i & 7;
        orow[i] = ((const bf16x8*)tile)[wp * 8 + (k ^ ((wp >> 2) & 7))];
    }
}

// ---------------- MFMA section machinery: ALL weights resident ----------------
#define MMA_CQ(dw, cq) do {                                                   \
    const int off_ = (((cq) * 32 + g16) ^ swz_);                              \
    const bf16x8 B0 = *(const bf16x8*)(ldsB + sl0 + wb_ + off_);              \
    const bf16x8 B1 = *(const bf16x8*)(ldsB + sl1 + wb_ + off_);              \
    const bf16x8 B2 = *(const bf16x8*)(ldsB + sl2 + wb_ + off_);              \
    const bf16x8 B3 = *(const bf16x8*)(ldsB + sl3 + wb_ + off_);              \
    const bf16x8 B4 = *(const bf16x8*)(ldsB + sl4 + wb_ + off_);              \
    const bf16x8 B5 = *(const bf16x8*)(ldsB + sl5 + wb_ + off_);              \
    a0 = MFMA(wfrag[(dw)*4 + (cq)], B0, a0, 0, 0, 0);                         \
    a1 = MFMA(wfrag[(dw)*4 + (cq)], B1, a1, 0, 0, 0);                         \
    a2 = MFMA(wfrag[(dw)*4 + (cq)], B2, a2, 0, 0, 0);                         \
    a3 = MFMA(wfrag[(dw)*4 + (cq)], B3, a3, 0, 0, 0);                         \
    a0 = MFMA(wfrag[12 + (dw)*4 + (cq)], B1, a0, 0, 0, 0);                    \
    a1 = MFMA(wfrag[12 + (dw)*4 + (cq)], B2, a1, 0, 0, 0);                    \
    a2 = MFMA(wfrag[12 + (dw)*4 + (cq)], B3, a2, 0, 0, 0);                    \
    a3 = MFMA(wfrag[12 + (dw)*4 + (cq)], B4, a3, 0, 0, 0);                    \
    a0 = MFMA(wfrag[24 + (dw)*4 + (cq)], B2, a0, 0, 0, 0);                    \
    a1 = MFMA(wfrag[24 + (dw)*4 + (cq)], B3, a1, 0, 0, 0);                    \
    a2 = MFMA(wfrag[24 + (dw)*4 + (cq)], B4, a2, 0, 0, 0);                    \
    a3 = MFMA(wfrag[24 + (dw)*4 + (cq)], B5, a3, 0, 0, 0);                    \
    SGB(0x100, 6, 0); SGB(0x008, 12, 0);                                      \
} while (0)

#define SECTION(dw, cqp) do {                                                 \
    const int wl_  = s + (dw);                                                \
    const int swz_ = (wl_ & 7) << 4;                                          \
    const int wb_  = wl_ * 128;                                               \
    MMA_CQ(dw, 2*(cqp));                                                      \
    MMA_CQ(dw, 2*(cqp) + 1);                                                  \
} while (0)

#define GLOAD_ROW(r) do {                                                     \
    const char* seg_ = xtn + (size_t)((r) + 1) * XT_ROWB;                     \
    char* lp_ = ldsB + (((r) + NSLOT) % NSLOT) * PLANE;                       \
    _Pragma("unroll")                                                         \
    for (int p_ = 0; p_ < 4; ++p_)                                            \
        __builtin_amdgcn_global_load_lds((GCHAR*)(seg_ + p_ * 1024 + lconst), \
                                         (LCHAR*)(lp_ + p_ * 1024), 16, 0, 0);\
    if (lane < 16)                                                            \
        __builtin_amdgcn_global_load_lds((GCHAR*)(seg_ + 4096 + lconst),      \
                                         (LCHAR*)(lp_ + 4096), 16, 0, 0);     \
} while (0)

// ---------------- conv, global_load_lds path (R15 + isolated XCD swizzle) ------------
__global__ __launch_bounds__(256, 2)
void conv3x3_gl(const unsigned short* __restrict__ xt, const unsigned short* __restrict__ wb,
                float* __restrict__ out) {
    __shared__ __align__(16) unsigned short lds[NSLOT * 34 * 64];  // 78336 B
    char* ldsB = (char*)lds;

    const int tid  = threadIdx.x;
    const int lane = tid & 63;
    const int wv   = tid >> 6;
    const int och  = wv & 1;
    const int rg4  = wv >> 1;
    const int s    = lane & 31;
    const int g    = lane >> 5;
    const int g16  = g * 16;

    // isolated XCD-chunked swizzle: dispatch d (XCD d%8) -> contiguous bid chunk
    const int bid = (blockIdx.x & 7) * 56 + (blockIdx.x >> 3);
    const int n   = bid / 28;
    const int rem = bid % 28;
    const int ws  = rem / 4;
    const int hc  = rem % 4;
    const int wbase = ws * 32;
    const int h0    = hc * 56;

    const int lconst = ((lane >> 3) << 7) + (((lane & 7) ^ (lane >> 3)) << 4);
    const char* xtn = (const char*)xt + (size_t)n * XT_NB + (size_t)wbase * 128;

    // ---- weights: ALL 36 K-step fragments resident (144 VGPR) ----
    const unsigned short* wlane = wb + g * 512 + (och * 32 + s) * 8;
    bf16x8 wfrag[36];
#pragma unroll
    for (int ks = 0; ks < 36; ++ks)
        wfrag[ks] = *(const bf16x8*)(wlane + ks * 1024);

    // ---- prologue: rows h0-1 .. h0+8 ----
    for (int rr = 0; rr < 10; ++rr) {
        const int r = h0 - 1 + rr;
        const char* seg = xtn + (size_t)(r + 1) * XT_ROWB;
        char* lp = ldsB + ((r + NSLOT) % NSLOT) * PLANE;
        __builtin_amdgcn_global_load_lds((GCHAR*)(seg + wv * 1024 + lconst),
                                         (LCHAR*)(lp + wv * 1024), 16, 0, 0);
        if (wv == 0 && lane < 16)
            __builtin_amdgcn_global_load_lds((GCHAR*)(seg + 4096 + lconst),
                                             (LCHAR*)(lp + 4096), 16, 0, 0);
    }
    __syncthreads();

#pragma unroll 1
    for (int it = 0; it < 7; ++it) {
        const int h  = h0 + 8 * it;
        const int hb = h + 4 * rg4;

        if (it < 6) {
            const int r0 = h + 9 + 2 * wv;
            GLOAD_ROW(r0);
            GLOAD_ROW(r0 + 1);
        }

        int t_ = (hb - 1 + NSLOT) % NSLOT;
        const int sl0 = t_ * PLANE; t_ = (t_ + 1 == NSLOT) ? 0 : t_ + 1;
        const int sl1 = t_ * PLANE; t_ = (t_ + 1 == NSLOT) ? 0 : t_ + 1;
        const int sl2 = t_ * PLANE; t_ = (t_ + 1 == NSLOT) ? 0 : t_ + 1;
        const int sl3 = t_ * PLANE; t_ = (t_ + 1 == NSLOT) ? 0 : t_ + 1;
        const int sl4 = t_ * PLANE; t_ = (t_ + 1 == NSLOT) ? 0 : t_ + 1;
        const int sl5 = t_ * PLANE;

        f32x16 a0 = {}, a1 = {}, a2 = {}, a3 = {};

        SECTION(0, 0);
        SECTION(0, 1);
        SECTION(1, 0);
        SECTION(1, 1);
        SECTION(2, 0);
        SECTION(2, 1);

        float* po = out + (n * 64 + och * 32 + 4 * g) * CHW + hb * WW + wbase + s;
#pragma unroll
        for (int rg = 0; rg < 16; ++rg) {
            const int o_ = ((rg & 3) + 8 * (rg >> 2)) * CHW;
            po[o_]          = a0[rg];
            po[o_ + WW]     = a1[rg];
            po[o_ + 2 * WW] = a2[rg];
            po[o_ + 3 * WW] = a3[rg];
        }

        __syncthreads();
    }
}

// ---------------- fallback: VGPR-staging conv (R8-style, dh2 streamed) ---------------
#define MMA_CQ_FB(dw, cq, WFU) do {                                           \
    const int off_ = (((cq) * 32 + g16) ^ swz_);                              \
    const bf16x8 B0 = *(const bf16x8*)(ldsB + sl0 + wb_ + off_);              \
    const bf16x8 B1 = *(const bf16x8*)(ldsB + sl1 + wb_ + off_);              \
    const bf16x8 B2 = *(const bf16x8*)(ldsB + sl2 + wb_ + off_);              \
    const bf16x8 B3 = *(const bf16x8*)(ldsB + sl3 + wb_ + off_);              \
    const bf16x8 B4 = *(const bf16x8*)(ldsB + sl4 + wb_ + off_);              \
    const bf16x8 B5 = *(const bf16x8*)(ldsB + sl5 + wb_ + off_);              \
    a0 = MFMA(wfragf[(dw)*4 + (cq)], B0, a0, 0, 0, 0);                        \
    a1 = MFMA(wfragf[(dw)*4 + (cq)], B1, a1, 0, 0, 0);                        \
    a2 = MFMA(wfragf[(dw)*4 + (cq)], B2, a2, 0, 0, 0);                        \
    a3 = MFMA(wfragf[(dw)*4 + (cq)], B3, a3, 0, 0, 0);                        \
    a0 = MFMA(wfragf[12 + (dw)*4 + (cq)], B1, a0, 0, 0, 0);                   \
    a1 = MFMA(wfragf[12 + (dw)*4 + (cq)], B2, a1, 0, 0, 0);                   \
    a2 = MFMA(wfragf[12 + (dw)*4 + (cq)], B3, a2, 0, 0, 0);                   \
    a3 = MFMA(wfragf[12 + (dw)*4 + (cq)], B4, a3, 0, 0, 0);                   \
    a0 = MFMA(WFU, B2, a0, 0, 0, 0);                                          \
    a1 = MFMA(WFU, B3, a1, 0, 0, 0);                                          \
    a2 = MFMA(WFU, B4, a2, 0, 0, 0);                                          \
    a3 = MFMA(WFU, B5, a3, 0, 0, 0);                                          \
    SGB(0x100, 6, 0); SGB(0x008, 12, 0);                                      \
} while (0)

#define SECTION_FB(dw, cqp, WFU0, WFU1, WFLD0, WFLD1, ldw, lcqp) do {         \
    WFLD0 = *(const bf16x8*)(wlane + ((6 + (ldw))*4 + 2*(lcqp)    ) * 1024);  \
    WFLD1 = *(const bf16x8*)(wlane + ((6 + (ldw))*4 + 2*(lcqp) + 1) * 1024);  \
    const int wl_  = s + (dw);                                                \
    const int swz_ = (wl_ & 7) << 4;                                          \
    const int wb_  = wl_ * 128;                                               \
    MMA_CQ_FB(dw, 2*(cqp),     WFU0);                                         \
    MMA_CQ_FB(dw, 2*(cqp) + 1, WFU1);                                         \
} while (0)

#define STI(k) do { if (st) {                                                 \
    const int r_ = h + 9 + (k);                                               \
    const bool ok_ = (r_ < HH);                                               \
    _Pragma("unroll")                                                         \
    for (int j = 0; j < 8; ++j) pv[j] = ok_ ? pxm[j*CHW + r_*WW] : 0.f;       \
    if (tid >= 240) {                                                         \
        const bool okh_ = ok_ && hokw;                                        \
        _Pragma("unroll")                                                     \
        for (int j = 0; j < 8; ++j) hv[j] = okh_ ? pxh[j*CHW + r_*WW] : 0.f;  \
    } } } while (0)

#define STW(k) do { if (st) {                                                 \
    int sw_ = slw + (k); if (sw_ >= NSLOT) sw_ -= NSLOT;                      \
    bf16x8 f_;                                                                \
    _Pragma("unroll")                                                         \
    for (int j = 0; j < 8; ++j) f_[j] = (short)f2bf(pv[j]);                   \
    *(bf16x8*)(ldsB + sw_ * PLANE + lom) = f_;                                \
    if (tid >= 240) {                                                         \
        bf16x8 fh_;                                                           \
        _Pragma("unroll")                                                     \
        for (int j = 0; j < 8; ++j) fh_[j] = (short)f2bf(hv[j]);              \
        *(bf16x8*)(ldsB + sw_ * PLANE + loh) = fh_;                           \
    } } } while (0)

__global__ __launch_bounds__(256, 2)
void conv3x3_fb(const float* __restrict__ x, const unsigned short* __restrict__ wb,
                float* __restrict__ out) {
    __shared__ __align__(16) unsigned short lds[NSLOT * 34 * 64];
    char* ldsB = (char*)lds;

    const int tid  = threadIdx.x;
    const int lane = tid & 63;
    const int wv   = tid >> 6;
    const int och  = wv & 1;
    const int rg4  = wv >> 1;
    const int s    = lane & 31;
    const int g    = lane >> 5;
    const int g16  = g * 16;

    const int bid = blockIdx.x;
    const int n   = bid / 28;
    const int rem = bid % 28;
    const int ws  = rem / 4;
    const int hc  = rem % 4;
    const int wbase = ws * 32;
    const int h0    = hc * 56;

    const unsigned short* wlane = wb + g * 512 + (och * 32 + s) * 8;
    bf16x8 wfragf[24];
#pragma unroll
    for (int ks = 0; ks < 24; ++ks)
        wfragf[ks] = *(const bf16x8*)(wlane + ks * 1024);
    bf16x8 wfA0 = *(const bf16x8*)(wlane + 24 * 1024);
    bf16x8 wfA1 = *(const bf16x8*)(wlane + 25 * 1024);
    bf16x8 wfB0 = {}, wfB1 = {};

    for (int p = tid; p < 10 * 272; p += 256) {
        const int rrel = p / 272;
        const int q  = p % 272;
        const int c8 = q / 34;
        const int wl = q % 34;
        const int r  = h0 - 1 + rrel;
        const int gw = wbase - 1 + wl;
        bf16x8 f = {};
        if (r >= 0 && r < HH && gw >= 0 && gw < WW) {
            const float* px = x + (n * 64 + c8 * 8) * CHW + r * WW + gw;
#pragma unroll
            for (int j = 0; j < 8; ++j) f[j] = (short)f2bf(px[j * CHW]);
        }
        *(bf16x8*)(ldsB + ((r + NSLOT) % NSLOT) * PLANE + wl * 128
                   + ((c8 * 16) ^ ((wl & 7) << 4))) = f;
    }

    const int c8m = tid >> 5;
    const int wlm = 1 + (tid & 31);
    const float* pxm = x + (n * 64 + c8m * 8) * CHW + (wbase + (tid & 31));
    const int lom = wlm * 128 + ((c8m * 16) ^ ((wlm & 7) << 4));
    const int c8h = lane & 7;
    const int wlh = ((lane >> 3) & 1) * 33;
    const int gwh = wbase - 1 + wlh;
    const bool hokw = (gwh >= 0 && gwh < WW);
    const float* pxh = x + (n * 64 + c8h * 8) * CHW + gwh;
    const int loh = wlh * 128 + ((c8h * 16) ^ ((wlh & 7) << 4));

    block_fence_lds();

#pragma unroll 1
    for (int it = 0; it < 7; ++it) {
        const int h  = h0 + 8 * it;
        const int hb = h + 4 * rg4;
        const bool st = (it < 6);
        const int slw = (h + 9) % NSLOT;

        int t_ = (hb - 1 + NSLOT) % NSLOT;
        const int sl0 = t_ * PLANE; t_ = (t_ + 1 == NSLOT) ? 0 : t_ + 1;
        const int sl1 = t_ * PLANE; t_ = (t_ + 1 == NSLOT) ? 0 : t_ + 1;
        const int sl2 = t_ * PLANE; t_ = (t_ + 1 == NSLOT) ? 0 : t_ + 1;
        const int sl3 = t_ * PLANE; t_ = (t_ + 1 == NSLOT) ? 0 : t_ + 1;
        const int sl4 = t_ * PLANE; t_ = (t_ + 1 == NSLOT) ? 0 : t_ + 1;
        const int sl5 = t_ * PLANE;

        float pv[8], hv[8];
        f32x16 a0 = {}, a1 = {}, a2 = {}, a3 = {};

        STI(0); SECTION_FB(0, 0, wfA0, wfA1, wfB0, wfB1, 0, 1); STW(0);
        STI(1); SECTION_FB(0, 1, wfB0, wfB1, wfA0, wfA1, 1, 0); STW(1);
        STI(2); SECTION_FB(1, 0, wfA0, wfA1, wfB0, wfB1, 1, 1); STW(2);
        STI(3); SECTION_FB(1, 1, wfB0, wfB1, wfA0, wfA1, 2, 0); STW(3);
        STI(4); SECTION_FB(2, 0, wfA0, wfA1, wfB0, wfB1, 2, 1); STW(4);
        STI(5); SECTION_FB(2, 1, wfB0, wfB1, wfA0, wfA1, 0, 0); STW(5);

        float* po = out + (n * 64 + och * 32 + 4 * g) * CHW + hb * WW + wbase + s;
        STI(6);
#pragma unroll
        for (int rg = 0; rg < 16; ++rg) {
            const int o_ = ((rg & 3) + 8 * (rg >> 2)) * CHW;
            po[o_]      = a0[rg];
            po[o_ + WW] = a1[rg];
        }
        STW(6); STI(7);
#pragma unroll
        for (int rg = 0; rg < 16; ++rg) {
            const int o_ = ((rg & 3) + 8 * (rg >> 2)) * CHW;
            po[o_ + 2 * WW] = a2[rg];
            po[o_ + 3 * WW] = a3[rg];
        }
        STW(7);

        block_fence_lds();
    }
}

extern "C" void kernel_launch(void* const* d_in, const int* in_sizes, int n_in,
                              void* d_out, int out_size, void* d_ws, size_t ws_size,
                              hipStream_t stream) {
    const float* x   = (const float*)d_in[0];
    const float* wgt = (const float*)d_in[1];
    float* out       = (float*)d_out;
    unsigned short* wbuf = (unsigned short*)d_ws;

    if (ws_size >= WS_NEED) {
        unsigned short* xt = (unsigned short*)((char*)d_ws + WB_BYTES);
        xprep_kernel<<<dim3(16 * 226), dim3(256), 0, stream>>>(x, wgt, wbuf, xt);
        conv3x3_gl<<<dim3(448), dim3(256), 0, stream>>>(xt, wbuf, out);
    } else {
        wprep_kernel<<<dim3(144), dim3(256), 0, stream>>>(wgt, wbuf);
        conv3x3_fb<<<dim3(448), dim3(256), 0, stream>>>(x, wbuf, out);
    }
}

// Round 17
// 157.394 us; speedup vs baseline: 1.0702x; 1.0702x over previous
//
#include <hip/hip_runtime.h>
#include <stdint.h>

// conv2d 3x3 s1 p1, NCHW fp32, N=16 C=K=64 H=W=224. Implicit GEMM bf16 MFMA 32x32x16.
// R17 = R15 exactly (161.6us plateau: 448 blocks default order, 18-slot ring,
// global_load_lds staging, all-36-resident weights, plain __syncthreads) plus ONLY
// the wprep-into-xprep merge (first 144 xprep blocks also convert weights; one less
// serialized dispatch). XCD swizzle removed (R13/R16: independently harmful).
// Fallback to R8-style VGPR-staging conv (with separate wprep) when ws too small.

#define HH 224
#define WW 224
#define CHW (HH * WW)
#define PLANE 4352           // 34 w * 64 c * 2 B
#define NSLOT 18
#define XT_ROWB 28928        // 226 wp * 64 c * 2 B per (n,hp) row
#define XT_NB   6537728      // 226 * XT_ROWB per n
#define WB_BYTES 73728
#define WS_NEED (WB_BYTES + 16 * (size_t)XT_NB)   // 104,677,376

typedef short bf16x8 __attribute__((ext_vector_type(8)));
typedef float f32x16 __attribute__((ext_vector_type(16)));
typedef __attribute__((address_space(1))) const char GCHAR;
typedef __attribute__((address_space(3))) char LCHAR;

__device__ __forceinline__ unsigned short f2bf(float f) {
    union { float f; unsigned int u; } v; v.f = f;
    unsigned int u = v.u;
    return (unsigned short)((u + 0x7fffu + ((u >> 16) & 1u)) >> 16);  // RNE
}

#define SGB  __builtin_amdgcn_sched_group_barrier
#define MFMA __builtin_amdgcn_mfma_f32_32x32x16_bf16

__device__ __forceinline__ void block_fence_lds() {
    asm volatile("s_waitcnt lgkmcnt(0)" ::: "memory");
    __builtin_amdgcn_s_barrier();
    __builtin_amdgcn_sched_barrier(0);
}

// ---------------- weight prep body (shared) ----------------
__device__ __forceinline__ void wprep_body(int i, const float* __restrict__ wgt,
                                           unsigned short* __restrict__ wb) {
    const int j   = i & 7;
    const int oc  = (i >> 3) & 63;
    const int g   = (i >> 9) & 1;
    const int ks  = i >> 10;
    const int tap = ks >> 2;
    const int c   = (ks & 3) * 16 + g * 8 + j;
    wb[i] = f2bf(wgt[(oc * 64 + c) * 9 + tap]);
}

__global__ void wprep_kernel(const float* __restrict__ wgt, unsigned short* __restrict__ wb) {
    const int i = blockIdx.x * 256 + threadIdx.x;
    if (i < 36864) wprep_body(i, wgt, wb);
}

// ---------------- input prep (+merged weight prep): NCHW fp32 -> padded CL bf16 ------
__global__ __launch_bounds__(256)
void xprep_kernel(const float* __restrict__ x, const float* __restrict__ wgt,
                  unsigned short* __restrict__ wb, unsigned short* __restrict__ xt) {
    __shared__ __align__(16) unsigned short tile[226 * 64];
    const int tid = threadIdx.x;
    const int b   = blockIdx.x;
    if (b < 144) wprep_body(b * 256 + tid, wgt, wb);   // merged weight prep

    const int n   = b / 226;
    const int hp  = b % 226;
    bf16x8* orow = (bf16x8*)((char*)xt + (size_t)(n * 226 + hp) * XT_ROWB);

    if (hp == 0 || hp == 225) {
        const bf16x8 z = {};
        for (int i = tid; i < 1808; i += 256) orow[i] = z;
        return;
    }
    if (tid < 64) { tile[tid] = 0; tile[225 * 64 + tid] = 0; }

    const float* xr = x + (size_t)n * 64 * CHW + (size_t)(hp - 1) * WW;
    for (int i = tid; i < 64 * 56; i += 256) {
        const int c  = i / 56;
        const int w4 = i % 56;
        const float4 v = *(const float4*)(xr + (size_t)c * CHW + w4 * 4);
        const int wp0 = w4 * 4 + 1;
        const int cb  = c * 2;
        *(unsigned short*)((char*)tile + (wp0    ) * 128 + (cb ^ ((((wp0    ) >> 2) & 7) << 4))) = f2bf(v.x);
        *(unsigned short*)((char*)tile + (wp0 + 1) * 128 + (cb ^ ((((wp0 + 1) >> 2) & 7) << 4))) = f2bf(v.y);
        *(unsigned short*)((char*)tile + (wp0 + 2) * 128 + (cb ^ ((((wp0 + 2) >> 2) & 7) << 4))) = f2bf(v.z);
        *(unsigned short*)((char*)tile + (wp0 + 3) * 128 + (cb ^ ((((wp0 + 3) >> 2) & 7) << 4))) = f2bf(v.w);
    }
    __syncthreads();
    for (int i = tid; i < 1808; i += 256) {
        const int wp = i >> 3, k = i & 7;
        orow[i] = ((const bf16x8*)tile)[wp * 8 + (k ^ ((wp >> 2) & 7))];
    }
}

// ---------------- MFMA section machinery: ALL weights resident ----------------
#define MMA_CQ(dw, cq) do {                                                   \
    const int off_ = (((cq) * 32 + g16) ^ swz_);                              \
    const bf16x8 B0 = *(const bf16x8*)(ldsB + sl0 + wb_ + off_);              \
    const bf16x8 B1 = *(const bf16x8*)(ldsB + sl1 + wb_ + off_);              \
    const bf16x8 B2 = *(const bf16x8*)(ldsB + sl2 + wb_ + off_);              \
    const bf16x8 B3 = *(const bf16x8*)(ldsB + sl3 + wb_ + off_);              \
    const bf16x8 B4 = *(const bf16x8*)(ldsB + sl4 + wb_ + off_);              \
    const bf16x8 B5 = *(const bf16x8*)(ldsB + sl5 + wb_ + off_);              \
    a0 = MFMA(wfrag[(dw)*4 + (cq)], B0, a0, 0, 0, 0);                         \
    a1 = MFMA(wfrag[(dw)*4 + (cq)], B1, a1, 0, 0, 0);                         \
    a2 = MFMA(wfrag[(dw)*4 + (cq)], B2, a2, 0, 0, 0);                         \
    a3 = MFMA(wfrag[(dw)*4 + (cq)], B3, a3, 0, 0, 0);                         \
    a0 = MFMA(wfrag[12 + (dw)*4 + (cq)], B1, a0, 0, 0, 0);                    \
    a1 = MFMA(wfrag[12 + (dw)*4 + (cq)], B2, a1, 0, 0, 0);                    \
    a2 = MFMA(wfrag[12 + (dw)*4 + (cq)], B3, a2, 0, 0, 0);                    \
    a3 = MFMA(wfrag[12 + (dw)*4 + (cq)], B4, a3, 0, 0, 0);                    \
    a0 = MFMA(wfrag[24 + (dw)*4 + (cq)], B2, a0, 0, 0, 0);                    \
    a1 = MFMA(wfrag[24 + (dw)*4 + (cq)], B3, a1, 0, 0, 0);                    \
    a2 = MFMA(wfrag[24 + (dw)*4 + (cq)], B4, a2, 0, 0, 0);                    \
    a3 = MFMA(wfrag[24 + (dw)*4 + (cq)], B5, a3, 0, 0, 0);                    \
    SGB(0x100, 6, 0); SGB(0x008, 12, 0);                                      \
} while (0)

#define SECTION(dw, cqp) do {                                                 \
    const int wl_  = s + (dw);                                                \
    const int swz_ = (wl_ & 7) << 4;                                          \
    const int wb_  = wl_ * 128;                                               \
    MMA_CQ(dw, 2*(cqp));                                                      \
    MMA_CQ(dw, 2*(cqp) + 1);                                                  \
} while (0)

#define GLOAD_ROW(r) do {                                                     \
    const char* seg_ = xtn + (size_t)((r) + 1) * XT_ROWB;                     \
    char* lp_ = ldsB + (((r) + NSLOT) % NSLOT) * PLANE;                       \
    _Pragma("unroll")                                                         \
    for (int p_ = 0; p_ < 4; ++p_)                                            \
        __builtin_amdgcn_global_load_lds((GCHAR*)(seg_ + p_ * 1024 + lconst), \
                                         (LCHAR*)(lp_ + p_ * 1024), 16, 0, 0);\
    if (lane < 16)                                                            \
        __builtin_amdgcn_global_load_lds((GCHAR*)(seg_ + 4096 + lconst),      \
                                         (LCHAR*)(lp_ + 4096), 16, 0, 0);     \
} while (0)

// ---------------- conv, global_load_lds path (R15 verbatim: no swizzle) --------------
__global__ __launch_bounds__(256, 2)
void conv3x3_gl(const unsigned short* __restrict__ xt, const unsigned short* __restrict__ wb,
                float* __restrict__ out) {
    __shared__ __align__(16) unsigned short lds[NSLOT * 34 * 64];  // 78336 B
    char* ldsB = (char*)lds;

    const int tid  = threadIdx.x;
    const int lane = tid & 63;
    const int wv   = tid >> 6;
    const int och  = wv & 1;
    const int rg4  = wv >> 1;
    const int s    = lane & 31;
    const int g    = lane >> 5;
    const int g16  = g * 16;

    const int bid = blockIdx.x;
    const int n   = bid / 28;
    const int rem = bid % 28;
    const int ws  = rem / 4;
    const int hc  = rem % 4;
    const int wbase = ws * 32;
    const int h0    = hc * 56;

    const int lconst = ((lane >> 3) << 7) + (((lane & 7) ^ (lane >> 3)) << 4);
    const char* xtn = (const char*)xt + (size_t)n * XT_NB + (size_t)wbase * 128;

    // ---- weights: ALL 36 K-step fragments resident (144 VGPR) ----
    const unsigned short* wlane = wb + g * 512 + (och * 32 + s) * 8;
    bf16x8 wfrag[36];
#pragma unroll
    for (int ks = 0; ks < 36; ++ks)
        wfrag[ks] = *(const bf16x8*)(wlane + ks * 1024);

    // ---- prologue: rows h0-1 .. h0+8 ----
    for (int rr = 0; rr < 10; ++rr) {
        const int r = h0 - 1 + rr;
        const char* seg = xtn + (size_t)(r + 1) * XT_ROWB;
        char* lp = ldsB + ((r + NSLOT) % NSLOT) * PLANE;
        __builtin_amdgcn_global_load_lds((GCHAR*)(seg + wv * 1024 + lconst),
                                         (LCHAR*)(lp + wv * 1024), 16, 0, 0);
        if (wv == 0 && lane < 16)
            __builtin_amdgcn_global_load_lds((GCHAR*)(seg + 4096 + lconst),
                                             (LCHAR*)(lp + 4096), 16, 0, 0);
    }
    __syncthreads();

#pragma unroll 1
    for (int it = 0; it < 7; ++it) {
        const int h  = h0 + 8 * it;
        const int hb = h + 4 * rg4;

        if (it < 6) {
            const int r0 = h + 9 + 2 * wv;
            GLOAD_ROW(r0);
            GLOAD_ROW(r0 + 1);
        }

        int t_ = (hb - 1 + NSLOT) % NSLOT;
        const int sl0 = t_ * PLANE; t_ = (t_ + 1 == NSLOT) ? 0 : t_ + 1;
        const int sl1 = t_ * PLANE; t_ = (t_ + 1 == NSLOT) ? 0 : t_ + 1;
        const int sl2 = t_ * PLANE; t_ = (t_ + 1 == NSLOT) ? 0 : t_ + 1;
        const int sl3 = t_ * PLANE; t_ = (t_ + 1 == NSLOT) ? 0 : t_ + 1;
        const int sl4 = t_ * PLANE; t_ = (t_ + 1 == NSLOT) ? 0 : t_ + 1;
        const int sl5 = t_ * PLANE;

        f32x16 a0 = {}, a1 = {}, a2 = {}, a3 = {};

        SECTION(0, 0);
        SECTION(0, 1);
        SECTION(1, 0);
        SECTION(1, 1);
        SECTION(2, 0);
        SECTION(2, 1);

        float* po = out + (n * 64 + och * 32 + 4 * g) * CHW + hb * WW + wbase + s;
#pragma unroll
        for (int rg = 0; rg < 16; ++rg) {
            const int o_ = ((rg & 3) + 8 * (rg >> 2)) * CHW;
            po[o_]          = a0[rg];
            po[o_ + WW]     = a1[rg];
            po[o_ + 2 * WW] = a2[rg];
            po[o_ + 3 * WW] = a3[rg];
        }

        __syncthreads();
    }
}

// ---------------- fallback: VGPR-staging conv (R8-style, dh2 streamed) ---------------
#define MMA_CQ_FB(dw, cq, WFU) do {                                           \
    const int off_ = (((cq) * 32 + g16) ^ swz_);                              \
    const bf16x8 B0 = *(const bf16x8*)(ldsB + sl0 + wb_ + off_);              \
    const bf16x8 B1 = *(const bf16x8*)(ldsB + sl1 + wb_ + off_);              \
    const bf16x8 B2 = *(const bf16x8*)(ldsB + sl2 + wb_ + off_);              \
    const bf16x8 B3 = *(const bf16x8*)(ldsB + sl3 + wb_ + off_);              \
    const bf16x8 B4 = *(const bf16x8*)(ldsB + sl4 + wb_ + off_);              \
    const bf16x8 B5 = *(const bf16x8*)(ldsB + sl5 + wb_ + off_);              \
    a0 = MFMA(wfragf[(dw)*4 + (cq)], B0, a0, 0, 0, 0);                        \
    a1 = MFMA(wfragf[(dw)*4 + (cq)], B1, a1, 0, 0, 0);                        \
    a2 = MFMA(wfragf[(dw)*4 + (cq)], B2, a2, 0, 0, 0);                        \
    a3 = MFMA(wfragf[(dw)*4 + (cq)], B3, a3, 0, 0, 0);                        \
    a0 = MFMA(wfragf[12 + (dw)*4 + (cq)], B1, a0, 0, 0, 0);                   \
    a1 = MFMA(wfragf[12 + (dw)*4 + (cq)], B2, a1, 0, 0, 0);                   \
    a2 = MFMA(wfragf[12 + (dw)*4 + (cq)], B3, a2, 0, 0, 0);                   \
    a3 = MFMA(wfragf[12 + (dw)*4 + (cq)], B4, a3, 0, 0, 0);                   \
    a0 = MFMA(WFU, B2, a0, 0, 0, 0);                                          \
    a1 = MFMA(WFU, B3, a1, 0, 0, 0);                                          \
    a2 = MFMA(WFU, B4, a2, 0, 0, 0);                                          \
    a3 = MFMA(WFU, B5, a3, 0, 0, 0);                                          \
    SGB(0x100, 6, 0); SGB(0x008, 12, 0);                                      \
} while (0)

#define SECTION_FB(dw, cqp, WFU0, WFU1, WFLD0, WFLD1, ldw, lcqp) do {         \
    WFLD0 = *(const bf16x8*)(wlane + ((6 + (ldw))*4 + 2*(lcqp)    ) * 1024);  \
    WFLD1 = *(const bf16x8*)(wlane + ((6 + (ldw))*4 + 2*(lcqp) + 1) * 1024);  \
    const int wl_  = s + (dw);                                                \
    const int swz_ = (wl_ & 7) << 4;                                          \
    const int wb_  = wl_ * 128;                                               \
    MMA_CQ_FB(dw, 2*(cqp),     WFU0);                                         \
    MMA_CQ_FB(dw, 2*(cqp) + 1, WFU1);                                         \
} while (0)

#define STI(k) do { if (st) {                                                 \
    const int r_ = h + 9 + (k);                                               \
    const bool ok_ = (r_ < HH);                                               \
    _Pragma("unroll")                                                         \
    for (int j = 0; j < 8; ++j) pv[j] = ok_ ? pxm[j*CHW + r_*WW] : 0.f;       \
    if (tid >= 240) {                                                         \
        const bool okh_ = ok_ && hokw;                                        \
        _Pragma("unroll")                                                     \
        for (int j = 0; j < 8; ++j) hv[j] = okh_ ? pxh[j*CHW + r_*WW] : 0.f;  \
    } } } while (0)

#define STW(k) do { if (st) {                                                 \
    int sw_ = slw + (k); if (sw_ >= NSLOT) sw_ -= NSLOT;                      \
    bf16x8 f_;                                                                \
    _Pragma("unroll")                                                         \
    for (int j = 0; j < 8; ++j) f_[j] = (short)f2bf(pv[j]);                   \
    *(bf16x8*)(ldsB + sw_ * PLANE + lom) = f_;                                \
    if (tid >= 240) {                                                         \
        bf16x8 fh_;                                                           \
        _Pragma("unroll")                                                     \
        for (int j = 0; j < 8; ++j) fh_[j] = (short)f2bf(hv[j]);              \
        *(bf16x8*)(ldsB + sw_ * PLANE + loh) = fh_;                           \
    } } } while (0)

__global__ __launch_bounds__(256, 2)
void conv3x3_fb(const float* __restrict__ x, const unsigned short* __restrict__ wb,
                float* __restrict__ out) {
    __shared__ __align__(16) unsigned short lds[NSLOT * 34 * 64];
    char* ldsB = (char*)lds;

    const int tid  = threadIdx.x;
    const int lane = tid & 63;
    const int wv   = tid >> 6;
    const int och  = wv & 1;
    const int rg4  = wv >> 1;
    const int s    = lane & 31;
    const int g    = lane >> 5;
    const int g16  = g * 16;

    const int bid = blockIdx.x;
    const int n   = bid / 28;
    const int rem = bid % 28;
    const int ws  = rem / 4;
    const int hc  = rem % 4;
    const int wbase = ws * 32;
    const int h0    = hc * 56;

    const unsigned short* wlane = wb + g * 512 + (och * 32 + s) * 8;
    bf16x8 wfragf[24];
#pragma unroll
    for (int ks = 0; ks < 24; ++ks)
        wfragf[ks] = *(const bf16x8*)(wlane + ks * 1024);
    bf16x8 wfA0 = *(const bf16x8*)(wlane + 24 * 1024);
    bf16x8 wfA1 = *(const bf16x8*)(wlane + 25 * 1024);
    bf16x8 wfB0 = {}, wfB1 = {};

    for (int p = tid; p < 10 * 272; p += 256) {
        const int rrel = p / 272;
        const int q  = p % 272;
        const int c8 = q / 34;
        const int wl = q % 34;
        const int r  = h0 - 1 + rrel;
        const int gw = wbase - 1 + wl;
        bf16x8 f = {};
        if (r >= 0 && r < HH && gw >= 0 && gw < WW) {
            const float* px = x + (n * 64 + c8 * 8) * CHW + r * WW + gw;
#pragma unroll
            for (int j = 0; j < 8; ++j) f[j] = (short)f2bf(px[j * CHW]);
        }
        *(bf16x8*)(ldsB + ((r + NSLOT) % NSLOT) * PLANE + wl * 128
                   + ((c8 * 16) ^ ((wl & 7) << 4))) = f;
    }

    const int c8m = tid >> 5;
    const int wlm = 1 + (tid & 31);
    const float* pxm = x + (n * 64 + c8m * 8) * CHW + (wbase + (tid & 31));
    const int lom = wlm * 128 + ((c8m * 16) ^ ((wlm & 7) << 4));
    const int c8h = lane & 7;
    const int wlh = ((lane >> 3) & 1) * 33;
    const int gwh = wbase - 1 + wlh;
    const bool hokw = (gwh >= 0 && gwh < WW);
    const float* pxh = x + (n * 64 + c8h * 8) * CHW + gwh;
    const int loh = wlh * 128 + ((c8h * 16) ^ ((wlh & 7) << 4));

    block_fence_lds();

#pragma unroll 1
    for (int it = 0; it < 7; ++it) {
        const int h  = h0 + 8 * it;
        const int hb = h + 4 * rg4;
        const bool st = (it < 6);
        const int slw = (h + 9) % NSLOT;

        int t_ = (hb - 1 + NSLOT) % NSLOT;
        const int sl0 = t_ * PLANE; t_ = (t_ + 1 == NSLOT) ? 0 : t_ + 1;
        const int sl1 = t_ * PLANE; t_ = (t_ + 1 == NSLOT) ? 0 : t_ + 1;
        const int sl2 = t_ * PLANE; t_ = (t_ + 1 == NSLOT) ? 0 : t_ + 1;
        const int sl3 = t_ * PLANE; t_ = (t_ + 1 == NSLOT) ? 0 : t_ + 1;
        const int sl4 = t_ * PLANE; t_ = (t_ + 1 == NSLOT) ? 0 : t_ + 1;
        const int sl5 = t_ * PLANE;

        float pv[8], hv[8];
        f32x16 a0 = {}, a1 = {}, a2 = {}, a3 = {};

        STI(0); SECTION_FB(0, 0, wfA0, wfA1, wfB0, wfB1, 0, 1); STW(0);
        STI(1); SECTION_FB(0, 1, wfB0, wfB1, wfA0, wfA1, 1, 0); STW(1);
        STI(2); SECTION_FB(1, 0, wfA0, wfA1, wfB0, wfB1, 1, 1); STW(2);
        STI(3); SECTION_FB(1, 1, wfB0, wfB1, wfA0, wfA1, 2, 0); STW(3);
        STI(4); SECTION_FB(2, 0, wfA0, wfA1, wfB0, wfB1, 2, 1); STW(4);
        STI(5); SECTION_FB(2, 1, wfB0, wfB1, wfA0, wfA1, 0, 0); STW(5);

        float* po = out + (n * 64 + och * 32 + 4 * g) * CHW + hb * WW + wbase + s;
        STI(6);
#pragma unroll
        for (int rg = 0; rg < 16; ++rg) {
            const int o_ = ((rg & 3) + 8 * (rg >> 2)) * CHW;
            po[o_]      = a0[rg];
            po[o_ + WW] = a1[rg];
        }
        STW(6); STI(7);
#pragma unroll
        for (int rg = 0; rg < 16; ++rg) {
            const int o_ = ((rg & 3) + 8 * (rg >> 2)) * CHW;
            po[o_ + 2 * WW] = a2[rg];
            po[o_ + 3 * WW] = a3[rg];
        }
        STW(7);

        block_fence_lds();
    }
}

extern "C" void kernel_launch(void* const* d_in, const int* in_sizes, int n_in,
                              void* d_out, int out_size, void* d_ws, size_t ws_size,
                              hipStream_t stream) {
    const float* x   = (const float*)d_in[0];
    const float* wgt = (const float*)d_in[1];
    float* out       = (float*)d_out;
    unsigned short* wbuf = (unsigned short*)d_ws;

    if (ws_size >= WS_NEED) {
        unsigned short* xt = (unsigned short*)((char*)d_ws + WB_BYTES);
        xprep_kernel<<<dim3(16 * 226), dim3(256), 0, stream>>>(x, wgt, wbuf, xt);
        conv3x3_gl<<<dim3(448), dim3(256), 0, stream>>>(xt, wbuf, out);
    } else {
        wprep_kernel<<<dim3(144), dim3(256), 0, stream>>>(wgt, wbuf);
        conv3x3_fb<<<dim3(448), dim3(256), 0, stream>>>(x, wbuf, out);
    }
}